// Round 18
// baseline (86.674 us; speedup 1.0000x reference)
//
#include <hip/hip_runtime.h>
#include <math.h>

#define Bdim 8
#define Cdim 64
#define Ndim 4096
#define TK   32            // keys per tile
#define GNT  32            // tiles per key-group (1024 keys / 32)

typedef __bf16 bf16x8 __attribute__((ext_vector_type(8)));
typedef __bf16 bf16x4 __attribute__((ext_vector_type(4)));
typedef float  f32x4  __attribute__((ext_vector_type(4)));
typedef float  f32x16 __attribute__((ext_vector_type(16)));

__device__ __forceinline__ void gload_lds16(const void* g, void* l) {
    __builtin_amdgcn_global_load_lds(
        (const __attribute__((address_space(1))) void*)g,
        (__attribute__((address_space(3))) void*)l, 16, 0, 0);
}

__device__ __forceinline__ float fexp2(float x) {
#if __has_builtin(__builtin_amdgcn_exp2f)
    return __builtin_amdgcn_exp2f(x);
#else
    return exp2f(x);
#endif
}

// ---------------------------------------------------------------------------
// Kernel 1: QKV projection via MFMA, hi/lo split (~fp32), fused W-conversion
// (r11/r13, validated). fgbias precompute (0 -> -12, masked -> -1e30).
// Q pre-scaled by (1/sqrt(C))*log2(e).
//   Qb [B][N][C], Kb [B][N][C], Vb [B][C][N]   (bf16)
// ---------------------------------------------------------------------------
__global__ __launch_bounds__(256) void qkv_mfma_kernel(
    const float* __restrict__ x, const float* __restrict__ w_qkv,
    const int* __restrict__ fg,
    __bf16* __restrict__ Qb, __bf16* __restrict__ Kb, __bf16* __restrict__ Vb,
    float* __restrict__ fgb)
{
    __shared__ __align__(16) __bf16 whs[64 * 64];
    __shared__ __align__(16) __bf16 wls[64 * 64];
    __shared__ __align__(16) __bf16 tr[4][16 * 64];

    const int bx   = blockIdx.x;
    const int jc   = bx % 3;                 // 0=Q, 1=K, 2=V
    const int nblk = (bx / 3) & 63;
    const int b    = bx / 192;
    const int tid  = threadIdx.x;
    const int wv   = tid >> 6;
    const int l    = tid & 63;
    const int g    = l >> 4;
    const int li   = l & 15;
    const int nbase = nblk * 64 + wv * 16;

    const float KS = 0.125f * 1.44269504089f;

    if (jc == 1 && tid < 64) {
        const int n = nblk * 64 + tid;
        fgb[b * Ndim + n] = fg[b * Ndim + n] ? -12.f : -1e30f;
    }

    // ---- convert this block's W slice into LDS hi/lo (swizzled) ----
    {
        const float* wsrc = w_qkv + jc * 4096 + tid * 16;
        const float4 f0 = *(const float4*)(wsrc);
        const float4 f1 = *(const float4*)(wsrc + 4);
        const float4 f2 = *(const float4*)(wsrc + 8);
        const float4 f3 = *(const float4*)(wsrc + 12);
        const int row = tid >> 2;
        const int gb  = (tid & 3) * 2;
        bf16x8 h0, l0, h1, l1;
        const float* fp[4] = {(const float*)&f0, (const float*)&f1,
                              (const float*)&f2, (const float*)&f3};
#pragma unroll
        for (int qq = 0; qq < 2; ++qq)
#pragma unroll
            for (int e = 0; e < 8; ++e) {
                const float v = fp[qq * 2 + (e >> 2)][e & 3];
                const __bf16 h = (__bf16)v;
                if (qq == 0) { h0[e] = h; l0[e] = (__bf16)(v - (float)h); }
                else         { h1[e] = h; l1[e] = (__bf16)(v - (float)h); }
            }
        *(bf16x8*)(whs + row * 64 + 8 * ((gb)     ^ (row & 7))) = h0;
        *(bf16x8*)(whs + row * 64 + 8 * ((gb + 1) ^ (row & 7))) = h1;
        *(bf16x8*)(wls + row * 64 + 8 * ((gb)     ^ (row & 7))) = l0;
        *(bf16x8*)(wls + row * 64 + 8 * ((gb + 1) ^ (row & 7))) = l1;
    }

    bf16x8 xhi[2], xlo[2];
#pragma unroll
    for (int kc = 0; kc < 2; ++kc)
#pragma unroll
        for (int jj = 0; jj < 8; ++jj) {
            const int c = kc * 32 + 8 * g + jj;
            const float v = x[((size_t)(b * 64 + c)) * Ndim + nbase + li];
            const __bf16 h = (__bf16)v;
            xhi[kc][jj] = h;
            xlo[kc][jj] = (__bf16)(v - (float)h);
        }
    __syncthreads();

    __bf16* trw = tr[wv];
    const float qs = (jc == 0) ? KS : 1.f;

#pragma unroll
    for (int jt = 0; jt < 4; ++jt) {
        const int rw = 16 * jt + li;
        const int rs = li & 7;
        const bf16x8 ah0 = *(const bf16x8*)(whs + rw * 64 + 8 * (g ^ rs));
        const bf16x8 ah1 = *(const bf16x8*)(whs + rw * 64 + 8 * ((4 + g) ^ rs));
        const bf16x8 al0 = *(const bf16x8*)(wls + rw * 64 + 8 * (g ^ rs));
        const bf16x8 al1 = *(const bf16x8*)(wls + rw * 64 + 8 * ((4 + g) ^ rs));
        f32x4 d = (f32x4){0.f, 0.f, 0.f, 0.f};
        d = __builtin_amdgcn_mfma_f32_16x16x32_bf16(ah0, xhi[0], d, 0, 0, 0);
        d = __builtin_amdgcn_mfma_f32_16x16x32_bf16(ah1, xhi[1], d, 0, 0, 0);
        d = __builtin_amdgcn_mfma_f32_16x16x32_bf16(ah0, xlo[0], d, 0, 0, 0);
        d = __builtin_amdgcn_mfma_f32_16x16x32_bf16(ah1, xlo[1], d, 0, 0, 0);
        d = __builtin_amdgcn_mfma_f32_16x16x32_bf16(al0, xhi[0], d, 0, 0, 0);
        d = __builtin_amdgcn_mfma_f32_16x16x32_bf16(al1, xhi[1], d, 0, 0, 0);

        if (jc == 2) {
#pragma unroll
            for (int r = 0; r < 4; ++r) {
                const int cv = jt * 16 + 4 * g + r;
                Vb[((size_t)(b * 64 + cv)) * Ndim + nbase + li] = (__bf16)d[r];
            }
        } else {
            bf16x4 pk;
#pragma unroll
            for (int r = 0; r < 4; ++r) pk[r] = (__bf16)(d[r] * qs);
            const int gran = (2 * jt + (g >> 1)) ^ (li & 7);
            *(bf16x4*)(trw + li * 64 + gran * 8 + 4 * (g & 1)) = pk;
        }
    }

    if (jc != 2) {
        __bf16* dstm = ((jc == 0) ? Qb : Kb) + ((size_t)b * Ndim + nbase) * 64;
#pragma unroll
        for (int p = 0; p < 2; ++p) {
            const int row = p * 8 + (l >> 3);
            const uint4 vr = *(const uint4*)(
                trw + row * 64 + ((l & 7) ^ (l >> 3)) * 8);
            *(uint4*)(dstm + row * 64 + 8 * (l & 7)) = vr;
        }
    }
}

// ---------------------------------------------------------------------------
// Kernel 2: MFMA flash attention, 32x32x16, fixed-shift softmax.
// r16 chain-split (QK: z1||z2; PV: 4 independent accumulators) with
// __launch_bounds__(512,2): allocator ceiling 256 VGPR so the splits stay
// in registers (r16 spilled at the pinned-64 budget). Occupancy remains
// LDS-capped at 2 blocks/CU (16 waves) provided VGPR <= 128.
// ---------------------------------------------------------------------------
__global__ __launch_bounds__(512, 2) void attn_kernel(
    const __bf16* __restrict__ Qb, const __bf16* __restrict__ Kb,
    const __bf16* __restrict__ Vb, const float* __restrict__ fgb,
    const float* __restrict__ w_proj, const float* __restrict__ b_proj,
    float* __restrict__ out)
{
    __shared__ __align__(16) __bf16 kt[4][2][TK * 64];   // [grp][buf][R][c]  32 KB
    __shared__ __align__(16) __bf16 vt[4][2][64 * TK];   // [grp][buf][c][k]  32 KB
    __shared__ __align__(16) float  mtf[4][2][TK];       // mask bias (f32)   1 KB

    const int bx   = blockIdx.x;
    const int b    = bx & 7;
    const int qblk = (bx >> 3) & 63;
    const int tid  = threadIdx.x;
    const int wv   = tid >> 6;
    const int grp  = wv >> 1;
    const int wsub = wv & 1;
    const int l    = tid & 63;
    const int q    = l & 31;
    const int hi   = l >> 5;

    // Q B-frags: B[k=8hi+j+16s][col=q]
    const int qrow = qblk * 64 + wsub * 32 + q;
    const __bf16* qbp = Qb + ((size_t)b * Ndim + qrow) * 64;
    bf16x8 qf[4];
#pragma unroll
    for (int s = 0; s < 4; ++s)
        qf[s] = *(const bf16x8*)(qbp + 16 * s + 8 * hi);

    // ---- staging geometry (r13 enriched swizzles, validated) ----
    const int kbase0 = grp * 1024;
    const __bf16* ksrcc[2];
    const __bf16* vsrcc[2];
    int kdst[2], vdst[2];
#pragma unroll
    for (int cc = 0; cc < 2; ++cc) {
        const int R  = wsub * 16 + cc * 8 + (l >> 3);
        const int pi = (R & 19) | ((R & 4) << 1) | ((R & 8) >> 1);  // swap b2<->b3
        ksrcc[cc] = Kb + ((size_t)b * Ndim + kbase0 + pi) * 64
                  + 8 * ((l & 7) ^ (R & 7) ^ (((R >> 3) & 3) << 1));
        kdst[cc]  = (wsub * 16 + cc * 8) * 64;
        const int row = wsub * 32 + cc * 16 + (l >> 2);
        vsrcc[cc] = Vb + ((size_t)(b * 64 + row)) * Ndim + kbase0
                  + 8 * ((l & 3) ^ (((row >> 1) ^ (row >> 3)) & 3));
        vdst[cc]  = (wsub * 32 + cc * 16) * TK;
    }
    const float* fgbp = fgb + b * Ndim + kbase0;

    auto stage = [&](int t, int buf) {
#pragma unroll
        for (int cc = 0; cc < 2; ++cc)
            gload_lds16(ksrcc[cc] + (size_t)t * (TK * 64), &kt[grp][buf][kdst[cc]]);
#pragma unroll
        for (int cc = 0; cc < 2; ++cc)
            gload_lds16(vsrcc[cc] + t * TK, &vt[grp][buf][vdst[cc]]);
        if (wsub == 0 && l < 8)
            gload_lds16(fgbp + t * 32 + l * 4, &mtf[grp][buf][0]);
    };

    f32x16 acc0a = {}, acc0b = {}, acc1a = {}, acc1b = {};
    f32x4  psv  = {};

    stage(0, 0);

    for (int it = 0; it < GNT; ++it) {
        const int buf = it & 1;
        __syncthreads();                  // tile resident
        if (it + 1 < GNT) stage(it + 1, buf ^ 1);

        // mask bias -> C-init of z1 only: z[r] = bias[key (r&7)+8hi+16(r>>3)]
        const float* mrow = &mtf[grp][buf][0];
        const f32x4 ma = *(const f32x4*)(mrow + 8 * hi);
        const f32x4 mb = *(const f32x4*)(mrow + 8 * hi + 4);
        const f32x4 mc = *(const f32x4*)(mrow + 16 + 8 * hi);
        const f32x4 md = *(const f32x4*)(mrow + 20 + 8 * hi);
        f32x16 z1;
#pragma unroll
        for (int r = 0; r < 4; ++r) {
            z1[r] = ma[r]; z1[4 + r] = mb[r]; z1[8 + r] = mc[r]; z1[12 + r] = md[r];
        }
        f32x16 z2 = {};

        // ---- S^T = K Q^T : two independent 2-deep MFMA chains ----
        __builtin_amdgcn_s_setprio(1);
        bf16x8 kf[4];
#pragma unroll
        for (int s = 0; s < 4; ++s)
            kf[s] = *(const bf16x8*)(
                &kt[grp][buf][q * 64
                    + 8 * ((hi + 2 * s) ^ (q & 7) ^ (((q >> 3) & 3) << 1))]);
        z1 = __builtin_amdgcn_mfma_f32_32x32x16_bf16(kf[0], qf[0], z1, 0, 0, 0);
        z2 = __builtin_amdgcn_mfma_f32_32x32x16_bf16(kf[2], qf[2], z2, 0, 0, 0);
        z1 = __builtin_amdgcn_mfma_f32_32x32x16_bf16(kf[1], qf[1], z1, 0, 0, 0);
        z2 = __builtin_amdgcn_mfma_f32_32x32x16_bf16(kf[3], qf[3], z2, 0, 0, 0);
        __builtin_amdgcn_s_setprio(0);
        const f32x16 z = z1 + z2;

        // ---- p = exp2(s); per-lane partial row-sums ----
        f32x16 p;
#pragma unroll
        for (int r = 0; r < 16; ++r) {
            p[r] = fexp2(z[r]);
            psv[r & 3] += p[r];
        }
        bf16x8 pb0, pb1;
#pragma unroll
        for (int j = 0; j < 8; ++j) {
            pb0[j] = (__bf16)p[j];
            pb1[j] = (__bf16)p[8 + j];
        }

        // ---- O^T += V^T P^T : 4 fully independent MFMAs ----
        __builtin_amdgcn_s_setprio(1);
        {
            const int c0  = q;
            const int cs0 = ((c0 >> 1) ^ (c0 >> 3)) & 3;
            const int c1  = 32 + q;
            const int cs1 = ((c1 >> 1) ^ (c1 >> 3)) & 3;
            const bf16x8 vf0 = *(const bf16x8*)(&vt[grp][buf][c0 * 32 + 8 * ((hi)     ^ cs0)]);
            const bf16x8 vf1 = *(const bf16x8*)(&vt[grp][buf][c0 * 32 + 8 * ((hi + 2) ^ cs0)]);
            const bf16x8 vg0 = *(const bf16x8*)(&vt[grp][buf][c1 * 32 + 8 * ((hi)     ^ cs1)]);
            const bf16x8 vg1 = *(const bf16x8*)(&vt[grp][buf][c1 * 32 + 8 * ((hi + 2) ^ cs1)]);
            acc0a = __builtin_amdgcn_mfma_f32_32x32x16_bf16(vf0, pb0, acc0a, 0, 0, 0);
            acc1a = __builtin_amdgcn_mfma_f32_32x32x16_bf16(vg0, pb0, acc1a, 0, 0, 0);
            acc0b = __builtin_amdgcn_mfma_f32_32x32x16_bf16(vf1, pb1, acc0b, 0, 0, 0);
            acc1b = __builtin_amdgcn_mfma_f32_32x32x16_bf16(vg1, pb1, acc1b, 0, 0, 0);
        }
        __builtin_amdgcn_s_setprio(0);
    }

    const f32x16 acc0 = acc0a + acc0b;
    const f32x16 acc1 = acc1a + acc1b;

    // ---- row-sum: horizontal + cross-hi (once) ----
    float lsum = (psv[0] + psv[1]) + (psv[2] + psv[3]);
    lsum += __shfl_xor(lsum, 32);

    // ---- 4-way merge via LDS overlay (plain sums, shared fixed shift) ----
    float* mlb = (float*)&kt[0][0][0];
    __syncthreads();

    auto chunk = [&](int cidx) -> float* {
        return (cidx < 4) ? (float*)&vt[0][0][0] + cidx * 2048
                          : mlb + 256 + (cidx - 4) * 2048;
    };

    if (grp > 0) {
        const int pp = grp - 1;
        if (l < 32) mlb[(pp * 2 + wsub) * 32 + l] = lsum;
        float* o = chunk(pp * 2 + wsub);
#pragma unroll
        for (int fi = 0; fi < 8; ++fi) {
            f32x4 v;
#pragma unroll
            for (int e = 0; e < 4; ++e)
                v[e] = (fi < 4) ? acc0[(fi & 3) * 4 + e] : acc1[(fi & 3) * 4 + e];
            *(f32x4*)(o + (fi * 64 + l) * 4) = v;
        }
    }
    __syncthreads();
    if (grp > 0) return;

    float Lt = lsum;
#pragma unroll
    for (int pp = 0; pp < 3; ++pp)
        Lt += mlb[(pp * 2 + wsub) * 32 + q];
    const float inv = 1.f / Lt;

    f32x16 m0 = acc0, m1 = acc1;
#pragma unroll
    for (int pp = 0; pp < 3; ++pp) {
        const float* o = chunk(pp * 2 + wsub);
#pragma unroll
        for (int fi = 0; fi < 8; ++fi) {
            const f32x4 v = *(const f32x4*)(o + (fi * 64 + l) * 4);
#pragma unroll
            for (int e = 0; e < 4; ++e) {
                if (fi < 4) m0[(fi & 3) * 4 + e] += v[e];
                else        m1[(fi & 3) * 4 + e] += v[e];
            }
        }
    }

    // ---- normalized O -> B-frags (sigma-permuted k order, lane-local) ----
    bf16x8 ob[4];
#pragma unroll
    for (int s = 0; s < 4; ++s)
#pragma unroll
        for (int j = 0; j < 8; ++j) {
            const float vv = (s < 2) ? m0[j + 8 * (s & 1)] : m1[j + 8 * (s & 1)];
            ob[s][j] = (__bf16)(vv * inv);
        }

    // ---- fused out-projection: W columns sigma-permuted to match ----
    const int nb = qblk * 64 + wsub * 32;
#pragma unroll
    for (int H = 0; H < 2; ++H) {
        const int co = 32 * H + q;
        f32x16 y = {};
#pragma unroll
        for (int s = 0; s < 4; ++s) {
            const float* wr = w_proj + co * 64 + 4 * hi + 16 * s;
            const float4 fA = *(const float4*)(wr);
            const float4 fB = *(const float4*)(wr + 8);
            bf16x8 wf;
            wf[0] = (__bf16)fA.x; wf[1] = (__bf16)fA.y;
            wf[2] = (__bf16)fA.z; wf[3] = (__bf16)fA.w;
            wf[4] = (__bf16)fB.x; wf[5] = (__bf16)fB.y;
            wf[6] = (__bf16)fB.z; wf[7] = (__bf16)fB.w;
            y = __builtin_amdgcn_mfma_f32_32x32x16_bf16(wf, ob[s], y, 0, 0, 0);
        }
#pragma unroll
        for (int rq = 0; rq < 4; ++rq) {
            const f32x4 bp = *(const f32x4*)(b_proj + 32 * H + 4 * hi + 8 * rq);
#pragma unroll
            for (int e = 0; e < 4; ++e) {
                const int co2 = 32 * H + e + 8 * rq + 4 * hi;
                out[((size_t)(b * 64 + co2)) * Ndim + nb + q] = y[rq * 4 + e] + bp[e];
            }
        }
    }
}

extern "C" void kernel_launch(void* const* d_in, const int* in_sizes, int n_in,
                              void* d_out, int out_size, void* d_ws, size_t ws_size,
                              hipStream_t stream) {
    const float* x      = (const float*)d_in[0];
    const int*   fg     = (const int*)d_in[1];
    const float* w_qkv  = (const float*)d_in[2];
    const float* w_proj = (const float*)d_in[3];
    const float* b_proj = (const float*)d_in[4];
    float* out = (float*)d_out;

    const size_t per = (size_t)Bdim * Cdim * Ndim;   // 2,097,152 elems
    __bf16* Qb  = (__bf16*)d_ws;
    __bf16* Kb  = Qb + per;
    __bf16* Vb  = Kb + per;
    float*  fgb = (float*)(Vb + per);                // 128 KB

    qkv_mfma_kernel<<<dim3(Bdim * (Ndim / 64) * 3), dim3(256), 0, stream>>>(
        x, w_qkv, fg, Qb, Kb, Vb, fgb);
    attn_kernel<<<dim3(Bdim * (Ndim / 64)), dim3(512), 0, stream>>>(
        Qb, Kb, Vb, fgb, w_proj, b_proj, out);
}

// Round 19
// 61.436 us; speedup vs baseline: 1.4108x; 1.4108x over previous
//
#include <hip/hip_runtime.h>
#include <math.h>

#define Bdim 8
#define Cdim 64
#define Ndim 4096
#define TK   32            // keys per tile
#define GNT  32            // tiles per key-group (1024 keys / 32)

typedef __bf16 bf16x8 __attribute__((ext_vector_type(8)));
typedef __bf16 bf16x4 __attribute__((ext_vector_type(4)));
typedef float  f32x4  __attribute__((ext_vector_type(4)));

__device__ __forceinline__ void gload_lds16(const void* g, void* l) {
    __builtin_amdgcn_global_load_lds(
        (const __attribute__((address_space(1))) void*)g,
        (__attribute__((address_space(3))) void*)l, 16, 0, 0);
}

__device__ __forceinline__ float fexp2(float x) {
#if __has_builtin(__builtin_amdgcn_exp2f)
    return __builtin_amdgcn_exp2f(x);
#else
    return exp2f(x);
#endif
}

// ---------------------------------------------------------------------------
// Kernel 1: QKV projection via MFMA, hi/lo split (~fp32 precision).
// Fused W-conversion: each block converts its 64x64 fp32 W slice to bf16
// hi/lo in LDS (XOR-swizzled granules, conflict-free A-frag reads).
// Grid = B * 64n * 3jc (one matrix per block) -> 6 blocks/CU, 6 waves/SIMD.
// Q pre-scaled by (1/sqrt(C))*log2(e).
//   Qb [B][N][C], Kb [B][N][C], Vb [B][C][N]   (bf16)
// Q/K stores via wave-private LDS transpose (validated r10).
// ---------------------------------------------------------------------------
__global__ __launch_bounds__(256) void qkv_mfma_kernel(
    const float* __restrict__ x, const float* __restrict__ w_qkv,
    __bf16* __restrict__ Qb, __bf16* __restrict__ Kb, __bf16* __restrict__ Vb)
{
    __shared__ __align__(16) __bf16 whs[64 * 64];   // 8 KB
    __shared__ __align__(16) __bf16 wls[64 * 64];   // 8 KB
    __shared__ __align__(16) __bf16 tr[4][16 * 64]; // 8 KB, wave-private

    const int bx   = blockIdx.x;
    const int jc   = bx % 3;                 // 0=Q, 1=K, 2=V
    const int nblk = (bx / 3) & 63;
    const int b    = bx / 192;
    const int tid  = threadIdx.x;
    const int wv   = tid >> 6;
    const int l    = tid & 63;
    const int g    = l >> 4;
    const int li   = l & 15;
    const int nbase = nblk * 64 + wv * 16;

    const float KS = 0.125f * 1.44269504089f;

    // ---- convert this block's W slice (rows jc*64..+63) into LDS hi/lo ----
    {
        const float* wsrc = w_qkv + jc * 4096 + tid * 16;
        const float4 f0 = *(const float4*)(wsrc);
        const float4 f1 = *(const float4*)(wsrc + 4);
        const float4 f2 = *(const float4*)(wsrc + 8);
        const float4 f3 = *(const float4*)(wsrc + 12);
        const int row = tid >> 2;
        const int gb  = (tid & 3) * 2;
        bf16x8 h0, l0, h1, l1;
        const float* fp[4] = {(const float*)&f0, (const float*)&f1,
                              (const float*)&f2, (const float*)&f3};
#pragma unroll
        for (int q = 0; q < 2; ++q)
#pragma unroll
            for (int e = 0; e < 8; ++e) {
                const float v = fp[q * 2 + (e >> 2)][e & 3];
                const __bf16 h = (__bf16)v;
                if (q == 0) { h0[e] = h; l0[e] = (__bf16)(v - (float)h); }
                else        { h1[e] = h; l1[e] = (__bf16)(v - (float)h); }
            }
        *(bf16x8*)(whs + row * 64 + 8 * ((gb)     ^ (row & 7))) = h0;
        *(bf16x8*)(whs + row * 64 + 8 * ((gb + 1) ^ (row & 7))) = h1;
        *(bf16x8*)(wls + row * 64 + 8 * ((gb)     ^ (row & 7))) = l0;
        *(bf16x8*)(wls + row * 64 + 8 * ((gb + 1) ^ (row & 7))) = l1;
    }

    // ---- X B-frags: B[k=kc*32+8g+jj][col=li], hi/lo split ----
    bf16x8 xhi[2], xlo[2];
#pragma unroll
    for (int kc = 0; kc < 2; ++kc)
#pragma unroll
        for (int jj = 0; jj < 8; ++jj) {
            const int c = kc * 32 + 8 * g + jj;
            const float v = x[((size_t)(b * 64 + c)) * Ndim + nbase + li];
            const __bf16 h = (__bf16)v;
            xhi[kc][jj] = h;
            xlo[kc][jj] = (__bf16)(v - (float)h);
        }
    __syncthreads();

    __bf16* trw = tr[wv];
    const float qs = (jc == 0) ? KS : 1.f;

#pragma unroll
    for (int jt = 0; jt < 4; ++jt) {
        const int rw = 16 * jt + li;
        const int rs = li & 7;               // rw & 7 == li & 7
        const bf16x8 ah0 = *(const bf16x8*)(whs + rw * 64 + 8 * (g ^ rs));
        const bf16x8 ah1 = *(const bf16x8*)(whs + rw * 64 + 8 * ((4 + g) ^ rs));
        const bf16x8 al0 = *(const bf16x8*)(wls + rw * 64 + 8 * (g ^ rs));
        const bf16x8 al1 = *(const bf16x8*)(wls + rw * 64 + 8 * ((4 + g) ^ rs));
        f32x4 d = (f32x4){0.f, 0.f, 0.f, 0.f};
        d = __builtin_amdgcn_mfma_f32_16x16x32_bf16(ah0, xhi[0], d, 0, 0, 0);
        d = __builtin_amdgcn_mfma_f32_16x16x32_bf16(ah1, xhi[1], d, 0, 0, 0);
        d = __builtin_amdgcn_mfma_f32_16x16x32_bf16(ah0, xlo[0], d, 0, 0, 0);
        d = __builtin_amdgcn_mfma_f32_16x16x32_bf16(ah1, xlo[1], d, 0, 0, 0);
        d = __builtin_amdgcn_mfma_f32_16x16x32_bf16(al0, xhi[0], d, 0, 0, 0);
        d = __builtin_amdgcn_mfma_f32_16x16x32_bf16(al1, xhi[1], d, 0, 0, 0);

        // lane holds D[j = 16jt+4g+r][n = nbase+li]
        if (jc == 2) {
#pragma unroll
            for (int r = 0; r < 4; ++r) {
                const int cv = jt * 16 + 4 * g + r;
                Vb[((size_t)(b * 64 + cv)) * Ndim + nbase + li] = (__bf16)d[r];
            }
        } else {
            bf16x4 pk;
#pragma unroll
            for (int r = 0; r < 4; ++r) pk[r] = (__bf16)(d[r] * qs);
            const int gran = (2 * jt + (g >> 1)) ^ (li & 7);
            *(bf16x4*)(trw + li * 64 + gran * 8 + 4 * (g & 1)) = pk;
        }
    }

    if (jc != 2) {
        __bf16* dstm = ((jc == 0) ? Qb : Kb) + ((size_t)b * Ndim + nbase) * 64;
#pragma unroll
        for (int p = 0; p < 2; ++p) {
            const int row = p * 8 + (l >> 3);
            const uint4 vr = *(const uint4*)(
                trw + row * 64 + ((l & 7) ^ (l >> 3)) * 8);
            *(uint4*)(dstm + row * 64 + 8 * (l & 7)) = vr;
        }
    }
}

// ---------------------------------------------------------------------------
// Kernel 2: MFMA flash attention, FIXED-SHIFT softmax (r9-validated loop).
// Batch->XCD block swizzle (b = bx&7) so each XCD's L2 holds one batch's
// K/V working set. 8 waves = 4 key-grps x 2 q-subtiles of 32 q-rows.
// ---------------------------------------------------------------------------
__global__ __launch_bounds__(512, 4) void attn_kernel(
    const __bf16* __restrict__ Qb, const __bf16* __restrict__ Kb,
    const __bf16* __restrict__ Vb, const int* __restrict__ fg,
    const float* __restrict__ w_proj, const float* __restrict__ b_proj,
    float* __restrict__ out)
{
    __shared__ __align__(16) __bf16 kt[4][2][TK * 64];   // [grp][buf][R][c]  32 KB
    __shared__ __align__(16) __bf16 vt[4][2][64 * TK];   // [grp][buf][c][k]  32 KB
    __shared__ __align__(16) float  mtf[4][2][TK];       // mask bias (f32)   1 KB

    const int bx   = blockIdx.x;
    const int b    = bx & 7;          // batch -> XCD (dispatch round-robins bx%8)
    const int qblk = (bx >> 3) & 63;
    const int tid  = threadIdx.x;
    const int wv   = tid >> 6;       // 0..7
    const int grp  = wv >> 1;        // key-group 0..3
    const int wsub = wv & 1;         // q-subtile 0..1
    const int l    = tid & 63;
    const int g    = l >> 4;
    const int li   = l & 15;

    // Q B-frags, 32 q-rows: lo = qblk*64 + wsub*32 + li, hi = +16
    const int qlo = qblk * 64 + wsub * 32 + li;
    const __bf16* qb_lo = Qb + ((size_t)b * Ndim + qlo) * 64;
    const bf16x8 qa0 = *(const bf16x8*)(qb_lo + 8 * g);
    const bf16x8 qa1 = *(const bf16x8*)(qb_lo + 32 + 8 * g);
    const bf16x8 qa2 = *(const bf16x8*)(qb_lo + 16 * 64 + 8 * g);
    const bf16x8 qa3 = *(const bf16x8*)(qb_lo + 16 * 64 + 32 + 8 * g);

    // ---- staging geometry (r8-validated) ----
    const int kbase0 = grp * 1024;
    const __bf16* ksrcc[2];
    const __bf16* vsrcc[2];
    int kdst[2], vdst[2];
#pragma unroll
    for (int cc = 0; cc < 2; ++cc) {
        const int R  = wsub * 16 + cc * 8 + (l >> 3);
        const int kk = 8 * ((R >> 2) & 3) + 4 * (R >> 4) + (R & 3);
        ksrcc[cc] = Kb + ((size_t)b * Ndim + kbase0 + kk) * 64 + 8 * ((l & 7) ^ (R & 7));
        kdst[cc]  = (wsub * 16 + cc * 8) * 64;
        const int row = wsub * 32 + cc * 16 + (l >> 2);
        vsrcc[cc] = Vb + ((size_t)(b * 64 + row)) * Ndim + kbase0
                  + 8 * ((l & 3) ^ ((row >> 1) & 3));
        vdst[cc]  = (wsub * 32 + cc * 16) * TK;
    }
    const int* fgp = fg + b * Ndim + kbase0;

    auto stage = [&](int t, int buf) {
#pragma unroll
        for (int cc = 0; cc < 2; ++cc)
            gload_lds16(ksrcc[cc] + (size_t)t * (TK * 64), &kt[grp][buf][kdst[cc]]);
#pragma unroll
        for (int cc = 0; cc < 2; ++cc)
            gload_lds16(vsrcc[cc] + t * TK, &vt[grp][buf][vdst[cc]]);
        if (wsub == 0 && l < TK)
            mtf[grp][buf][l] = fgp[t * TK + l] ? -12.f : -1e30f;
    };

    f32x4 accl[4], acch[4];
#pragma unroll
    for (int ct = 0; ct < 4; ++ct) {
        accl[ct] = (f32x4){0.f, 0.f, 0.f, 0.f};
        acch[ct] = (f32x4){0.f, 0.f, 0.f, 0.f};
    }
    f32x4 psv_l = (f32x4){0.f, 0.f, 0.f, 0.f};
    f32x4 psv_h = (f32x4){0.f, 0.f, 0.f, 0.f};

    stage(0, 0);

    for (int it = 0; it < GNT; ++it) {
        const int buf = it & 1;
        __syncthreads();                  // tile resident
        if (it + 1 < GNT) stage(it + 1, buf ^ 1);

        // mask+shift bias, direct f32x4 reads: keys 8g+4st+r
        const f32x4 mb0 = *(const f32x4*)(&mtf[grp][buf][8 * g]);
        const f32x4 mb1 = *(const f32x4*)(&mtf[grp][buf][8 * g + 4]);

        // ---- S^T = K Q^T + (mask-12) acc-init; kb frags reused lo & hi ----
        f32x4 s2l[2], s2h[2];
        __builtin_amdgcn_s_setprio(1);
#pragma unroll
        for (int st = 0; st < 2; ++st) {
            const int rb = (16 * st + li) * 64;
            const int sw = li & 7;
            const bf16x8 kb0 = *(const bf16x8*)(&kt[grp][buf][rb + 8 * (g ^ sw)]);
            const bf16x8 kb1 = *(const bf16x8*)(&kt[grp][buf][rb + 8 * ((4 + g) ^ sw)]);
            f32x4 zl = st ? mb1 : mb0;
            zl = __builtin_amdgcn_mfma_f32_16x16x32_bf16(kb0, qa0, zl, 0, 0, 0);
            zl = __builtin_amdgcn_mfma_f32_16x16x32_bf16(kb1, qa1, zl, 0, 0, 0);
            s2l[st] = zl;
            f32x4 zh = st ? mb1 : mb0;
            zh = __builtin_amdgcn_mfma_f32_16x16x32_bf16(kb0, qa2, zh, 0, 0, 0);
            zh = __builtin_amdgcn_mfma_f32_16x16x32_bf16(kb1, qa3, zh, 0, 0, 0);
            s2h[st] = zh;
        }
        __builtin_amdgcn_s_setprio(0);

        // ---- p = exp2(s); per-lane partial row-sums (no cross-lane ops) ----
#pragma unroll
        for (int st = 0; st < 2; ++st)
#pragma unroll
            for (int r = 0; r < 4; ++r) {
                const float el = fexp2(s2l[st][r]);
                const float eh = fexp2(s2h[st][r]);
                s2l[st][r] = el; psv_l[r] += el;
                s2h[st][r] = eh; psv_h[r] += eh;
            }

        // ---- P B-frags (single K=32 frag each) = lane's own registers ----
        bf16x8 pbl, pbh;
#pragma unroll
        for (int r = 0; r < 4; ++r) {
            pbl[r]     = (__bf16)s2l[0][r];
            pbl[4 + r] = (__bf16)s2l[1][r];
            pbh[r]     = (__bf16)s2h[0][r];
            pbh[4 + r] = (__bf16)s2h[1][r];
        }

        // ---- O^T += V^T P^T : one b128 V A-frag per ct, reused lo & hi ----
        __builtin_amdgcn_s_setprio(1);
#pragma unroll
        for (int ct = 0; ct < 4; ++ct) {
            const int c = 16 * ct + li;
            const bf16x8 vf = *(const bf16x8*)(
                &vt[grp][buf][c * TK + 8 * (g ^ ((li >> 1) & 3))]);
            accl[ct] = __builtin_amdgcn_mfma_f32_16x16x32_bf16(vf, pbl, accl[ct], 0, 0, 0);
            acch[ct] = __builtin_amdgcn_mfma_f32_16x16x32_bf16(vf, pbh, acch[ct], 0, 0, 0);
        }
        __builtin_amdgcn_s_setprio(0);
    }

    // ---- row-sum: horizontal + cross-g (once, at end) ----
    float lsum_l = (psv_l[0] + psv_l[1]) + (psv_l[2] + psv_l[3]);
    float lsum_h = (psv_h[0] + psv_h[1]) + (psv_h[2] + psv_h[3]);
    lsum_l += __shfl_xor(lsum_l, 16);
    lsum_l += __shfl_xor(lsum_l, 32);
    lsum_h += __shfl_xor(lsum_h, 16);
    lsum_h += __shfl_xor(lsum_h, 32);

    // ---- 4-way merge via LDS overlay: plain sums (shared fixed shift) ----
    float* mlb = (float*)&kt[0][0][0];
    __syncthreads();                     // all tile reads done

    auto chunk = [&](int cidx) -> float* {
        return (cidx < 4) ? (float*)&vt[0][0][0] + cidx * 2048
                          : mlb + 256 + (cidx - 4) * 2048;
    };

    if (grp > 0) {
        const int p = grp - 1;
        if (g == 0) {
            mlb[((p * 2 + wsub) * 2 + 0) * 16 + li] = lsum_l;
            mlb[((p * 2 + wsub) * 2 + 1) * 16 + li] = lsum_h;
        }
        float* o = chunk(p * 2 + wsub);
#pragma unroll
        for (int fi = 0; fi < 8; ++fi)
            *(f32x4*)(o + (fi * 64 + l) * 4) = (fi < 4) ? accl[fi] : acch[fi - 4];
    }
    __syncthreads();
    if (grp > 0) return;

    float Ltl = lsum_l, Lth = lsum_h;
#pragma unroll
    for (int p = 0; p < 3; ++p) {
        Ltl += mlb[((p * 2 + wsub) * 2 + 0) * 16 + li];
        Lth += mlb[((p * 2 + wsub) * 2 + 1) * 16 + li];
    }
    const float invl = 1.f / Ltl, invh = 1.f / Lth;

    bf16x8 ob01l, ob23l, ob01h, ob23h;
#pragma unroll
    for (int fi = 0; fi < 8; ++fi) {
        const int  ct = fi & 3;
        const bool hi = fi >= 4;
        f32x4 s = hi ? acch[ct] : accl[ct];
#pragma unroll
        for (int p = 0; p < 3; ++p) {
            const f32x4 v = *(const f32x4*)(chunk(p * 2 + wsub) + (fi * 64 + l) * 4);
#pragma unroll
            for (int r = 0; r < 4; ++r) s[r] += v[r];
        }
        const float inv = hi ? invh : invl;
#pragma unroll
        for (int r = 0; r < 4; ++r) {
            const __bf16 o = (__bf16)(s[r] * inv);
            if (fi == 0) ob01l[r] = o;
            else if (fi == 1) ob01l[4 + r] = o;
            else if (fi == 2) ob23l[r] = o;
            else if (fi == 3) ob23l[4 + r] = o;
            else if (fi == 4) ob01h[r] = o;
            else if (fi == 5) ob01h[4 + r] = o;
            else if (fi == 6) ob23h[r] = o;
            else              ob23h[4 + r] = o;
        }
    }

    // ---- fused out-projection (w frags reused lo & hi) ----
    const int nbase = qblk * 64 + wsub * 32;
#pragma unroll
    for (int cot = 0; cot < 4; ++cot) {
        const int co = 16 * cot + li;
        const float* wr = w_proj + co * 64;
        const float4 f0 = *(const float4*)(wr + 4 * g);
        const float4 f1 = *(const float4*)(wr + 16 + 4 * g);
        const float4 f2 = *(const float4*)(wr + 32 + 4 * g);
        const float4 f3 = *(const float4*)(wr + 48 + 4 * g);
        bf16x8 wf0, wf1;
        wf0[0] = (__bf16)f0.x; wf0[1] = (__bf16)f0.y; wf0[2] = (__bf16)f0.z; wf0[3] = (__bf16)f0.w;
        wf0[4] = (__bf16)f1.x; wf0[5] = (__bf16)f1.y; wf0[6] = (__bf16)f1.z; wf0[7] = (__bf16)f1.w;
        wf1[0] = (__bf16)f2.x; wf1[1] = (__bf16)f2.y; wf1[2] = (__bf16)f2.z; wf1[3] = (__bf16)f2.w;
        wf1[4] = (__bf16)f3.x; wf1[5] = (__bf16)f3.y; wf1[6] = (__bf16)f3.z; wf1[7] = (__bf16)f3.w;

        f32x4 yl = (f32x4){0.f, 0.f, 0.f, 0.f};
        yl = __builtin_amdgcn_mfma_f32_16x16x32_bf16(wf0, ob01l, yl, 0, 0, 0);
        yl = __builtin_amdgcn_mfma_f32_16x16x32_bf16(wf1, ob23l, yl, 0, 0, 0);
        f32x4 yh = (f32x4){0.f, 0.f, 0.f, 0.f};
        yh = __builtin_amdgcn_mfma_f32_16x16x32_bf16(wf0, ob01h, yh, 0, 0, 0);
        yh = __builtin_amdgcn_mfma_f32_16x16x32_bf16(wf1, ob23h, yh, 0, 0, 0);

        const f32x4 bp = *(const f32x4*)(b_proj + 16 * cot + 4 * g);
#pragma unroll
        for (int r = 0; r < 4; ++r) {
            const int co_s = 16 * cot + 4 * g + r;
            float* orow = out + ((size_t)(b * 64 + co_s)) * Ndim + nbase;
            orow[li]      = yl[r] + bp[r];
            orow[16 + li] = yh[r] + bp[r];
        }
    }
}

extern "C" void kernel_launch(void* const* d_in, const int* in_sizes, int n_in,
                              void* d_out, int out_size, void* d_ws, size_t ws_size,
                              hipStream_t stream) {
    const float* x      = (const float*)d_in[0];
    const int*   fg     = (const int*)d_in[1];
    const float* w_qkv  = (const float*)d_in[2];
    const float* w_proj = (const float*)d_in[3];
    const float* b_proj = (const float*)d_in[4];
    float* out = (float*)d_out;

    const size_t per = (size_t)Bdim * Cdim * Ndim;   // 2,097,152 elems
    __bf16* Qb = (__bf16*)d_ws;
    __bf16* Kb = Qb + per;
    __bf16* Vb = Kb + per;

    qkv_mfma_kernel<<<dim3(Bdim * (Ndim / 64) * 3), dim3(256), 0, stream>>>(
        x, w_qkv, Qb, Kb, Vb);
    attn_kernel<<<dim3(Bdim * (Ndim / 64)), dim3(512), 0, stream>>>(
        Qb, Kb, Vb, fg, w_proj, b_proj, out);
}